// Round 6
// baseline (711.276 us; speedup 1.0000x reference)
//
#include <hip/hip_runtime.h>
#include <hip/hip_bf16.h>

#define WIN 11
#define PAD 5
#define TW 32           // tile width (output cols)
#define TH 64           // tile height (output rows)
#define IH 74           // TH + 2*PAD rows processed by h-pass
#define HSTR 33         // h-pass row stride (pixels)
#define IMG_H 512
#define IMG_W 512
#define BLK 512

// ---------------- main fused SSIM kernel ----------------
// No input staging: h-pass reads img1/img2 directly from global (L1/L2-hot
// overlapping windows). LDS holds only the h-pass intermediates -> 48.9 KB
// -> 3 blocks/CU (24 waves, vs 2 blocks/16 waves with staged inputs).
__global__ __launch_bounds__(BLK, 6) void ssim_main(const float* __restrict__ img1,
                                                    const float* __restrict__ img2,
                                                    float* __restrict__ partial) {
    __shared__ float4 h4[IH * HSTR];          // 39072 B : (sx, sy, sxx, syy)
    __shared__ float  h1[IH * HSTR];          // 9768 B  : sxy
    __shared__ float  wsum[8];

    const int tid = threadIdx.x;
    const int tx0 = blockIdx.x * TW;
    const int ty0 = blockIdx.y * TH;
    const size_t base = (size_t)blockIdx.z * (size_t)(IMG_H * IMG_W);

    // Gaussian weights (match jnp: exp(-d^2/(2*1.5^2)), normalized, f32)
    float g[WIN];
    {
        float s = 0.f;
#pragma unroll
        for (int i = 0; i < WIN; ++i) {
            float d = (float)(i - PAD);
            g[i] = expf(-d * d / 4.5f);
            s += g[i];
        }
        float inv = 1.f / s;
#pragma unroll
        for (int i = 0; i < WIN; ++i) g[i] *= inv;
    }

    const bool interior = (blockIdx.x >= 1) & (blockIdx.x <= (IMG_W / TW - 2)) &
                          (blockIdx.y >= 1) & (blockIdx.y <= (IMG_H / TH - 2));

    // ---- horizontal 11-tap pass: 4 outputs/thread, inputs from global ----
    // Task remap: 8 consecutive lanes -> 8 different rows, same chunk group
    // (keeps h4/h1 LDS writes bank-conflict-minimal, per R4 measurement).
    // Output cols tx0+4*c0g .. +3 need global cols tx0-8+4*c0g .. +19
    // (5 aligned float4 chunks; 512%4==0 so chunks are wholly in/out).
    for (int t = tid; t < IH * 8 + 48; t += BLK) {   // 592 tasks padded
        int c0g = (t >> 3) & 7;
        int r = (t & 7) + ((t >> 6) << 3);
        if (r < IH) {
            int gr = ty0 + r - PAD;
            float ax[20], bx[20];
            if (interior) {
                const float* q1 = img1 + base + (size_t)gr * IMG_W + (tx0 - 8 + 4 * c0g);
                const float* q2 = img2 + base + (size_t)gr * IMG_W + (tx0 - 8 + 4 * c0g);
#pragma unroll
                for (int j = 0; j < 5; ++j) {
                    float4 va = *(const float4*)(q1 + 4 * j);
                    float4 vb = *(const float4*)(q2 + 4 * j);
                    ax[4 * j + 0] = va.x; ax[4 * j + 1] = va.y; ax[4 * j + 2] = va.z; ax[4 * j + 3] = va.w;
                    bx[4 * j + 0] = vb.x; bx[4 * j + 1] = vb.y; bx[4 * j + 2] = vb.z; bx[4 * j + 3] = vb.w;
                }
            } else {
                const bool rowok = (unsigned)gr < (unsigned)IMG_H;
                const size_t rowoff = base + (size_t)(rowok ? gr : 0) * IMG_W;
#pragma unroll
                for (int j = 0; j < 5; ++j) {
                    int gc = tx0 - 8 + 4 * (c0g + j);
                    float4 va = make_float4(0.f, 0.f, 0.f, 0.f);
                    float4 vb = make_float4(0.f, 0.f, 0.f, 0.f);
                    if (rowok && (unsigned)gc < (unsigned)IMG_W) {
                        va = *(const float4*)(img1 + rowoff + gc);
                        vb = *(const float4*)(img2 + rowoff + gc);
                    }
                    ax[4 * j + 0] = va.x; ax[4 * j + 1] = va.y; ax[4 * j + 2] = va.z; ax[4 * j + 3] = va.w;
                    bx[4 * j + 0] = vb.x; bx[4 * j + 1] = vb.y; bx[4 * j + 2] = vb.z; bx[4 * j + 3] = vb.w;
                }
            }
#pragma unroll
            for (int cc = 0; cc < 4; ++cc) {
                float sx = 0.f, sy = 0.f, sxx = 0.f, syy = 0.f, sxy = 0.f;
#pragma unroll
                for (int j = 0; j < WIN; ++j) {
                    float w = g[j];
                    float a = ax[cc + 3 + j];
                    float b = bx[cc + 3 + j];
                    float wa = w * a, wb = w * b;
                    sx += wa;
                    sy += wb;
                    sxx = fmaf(wa, a, sxx);
                    syy = fmaf(wb, b, syy);
                    sxy = fmaf(wa, b, sxy);
                }
                int o = r * HSTR + 4 * c0g + cc;
                h4[o] = make_float4(sx, sy, sxx, syy);
                h1[o] = sxy;
            }
        }
    }
    __syncthreads();

    // ---- vertical 11-tap pass + SSIM map: 4 outputs/thread in a column ----
    const float C2v = 0.0009f;  // (0.03 * 1.0)^2
    float acc = 0.f;
    {
        int c = tid & 31;
        int r0 = (tid >> 5) * 4;           // 16 row-groups x 32 cols = 512 tasks
        float vsx[4] = {0.f, 0.f, 0.f, 0.f};
        float vsy[4] = {0.f, 0.f, 0.f, 0.f};
        float vxx[4] = {0.f, 0.f, 0.f, 0.f};
        float vyy[4] = {0.f, 0.f, 0.f, 0.f};
        float vxy[4] = {0.f, 0.f, 0.f, 0.f};
#pragma unroll
        for (int i = 0; i < WIN + 3; ++i) {
            float4 h = h4[(r0 + i) * HSTR + c];
            float  e = h1[(r0 + i) * HSTR + c];
#pragma unroll
            for (int k = 0; k < 4; ++k) {
                if (i >= k && i <= k + 10) {
                    float w = g[i - k];
                    vsx[k] = fmaf(w, h.x, vsx[k]);
                    vsy[k] = fmaf(w, h.y, vsy[k]);
                    vxx[k] = fmaf(w, h.z, vxx[k]);
                    vyy[k] = fmaf(w, h.w, vyy[k]);
                    vxy[k] = fmaf(w, e,  vxy[k]);
                }
            }
        }
#pragma unroll
        for (int k = 0; k < 4; ++k) {
            float mu12 = vsx[k] * vsy[k];
            float s1 = vxx[k] - vsx[k] * vsx[k];
            float s2 = vyy[k] - vsy[k] * vsy[k];
            float s12 = vxy[k] - mu12;
            float sig = sqrtf(fabsf(s1)) * sqrtf(fabsf(s2));
            acc += (s12 + C2v) / (sig + C2v);
        }
    }

    // ---- block reduction -> one float partial per block ----
#pragma unroll
    for (int off = 32; off > 0; off >>= 1) acc += __shfl_down(acc, off, 64);
    int wave = tid >> 6;
    if ((tid & 63) == 0) wsum[wave] = acc;
    __syncthreads();
    if (tid == 0) {
        float b = 0.f;
#pragma unroll
        for (int w = 0; w < BLK / 64; ++w) b += wsum[w];
        int bid = (blockIdx.z * gridDim.y + blockIdx.y) * gridDim.x + blockIdx.x;
        partial[bid] = b;
    }
}

// ---------------- final reduction ----------------
__global__ __launch_bounds__(1024) void ssim_final(const float* __restrict__ partial,
                                                   int n, float* __restrict__ out,
                                                   double inv_total) {
    __shared__ double wsd[16];
    double s = 0.0;
    const float4* p4 = (const float4*)partial;
    for (int i = threadIdx.x; i < n / 4; i += 1024) {
        float4 v = p4[i];
        s += (double)v.x + (double)v.y + (double)v.z + (double)v.w;
    }
#pragma unroll
    for (int off = 32; off > 0; off >>= 1) s += __shfl_down(s, off, 64);
    int wave = threadIdx.x >> 6;
    if ((threadIdx.x & 63) == 0) wsd[wave] = s;
    __syncthreads();
    if (threadIdx.x == 0) {
        double t = 0.0;
#pragma unroll
        for (int w = 0; w < 16; ++w) t += wsd[w];
        out[0] = (float)(t * inv_total);
    }
}

extern "C" void kernel_launch(void* const* d_in, const int* in_sizes, int n_in,
                              void* d_out, int out_size, void* d_ws, size_t ws_size,
                              hipStream_t stream) {
    const float* img1 = (const float*)d_in[0];
    const float* img2 = (const float*)d_in[1];
    float* out = (float*)d_out;
    float* partial = (float*)d_ws;

    const int total = in_sizes[0];                  // 32*3*512*512
    const int nc = total / (IMG_H * IMG_W);         // 96 images of 512x512

    dim3 grid(IMG_W / TW, IMG_H / TH, nc);          // 16 x 8 x 96 = 12288 blocks
    const int nblocks = grid.x * grid.y * grid.z;   // divisible by 4

    ssim_main<<<grid, BLK, 0, stream>>>(img1, img2, partial);
    ssim_final<<<1, 1024, 0, stream>>>(partial, nblocks, out, 1.0 / (double)total);
}

// Round 9
// 288.419 us; speedup vs baseline: 2.4661x; 2.4661x over previous
//
#include <hip/hip_runtime.h>

typedef float v2f __attribute__((ext_vector_type(2), may_alias));
typedef float v4f __attribute__((ext_vector_type(4), may_alias));

#define WIN 11
#define PAD 5
#define TW 32            // tile width (output cols)
#define TH 64            // tile height (output rows)
#define IH 74            // TH + 2*PAD staged rows
#define LAB4STR 25       // float4 per staged row (24 used + 1 pad = 25 quads, odd -> conflict-min)
#define PSTR 78          // v2f row stride of col-major h-planes (624B; /16 = 39 odd)
#define P4STR 76         // f32 row stride of col-major sxy plane (304B; /16 = 19 odd)
#define IMG_H 512
#define IMG_W 512
#define BLK 512

// Gaussian weights for sigma=1.5, 11 taps, normalized (precomputed; error vs
// XLA's runtime f32 expf ~1e-7, negligible vs 3.8e-4 threshold). Saves ~25us
// of per-thread expf VALU measured in R4.
#define G_INIT {0.00102838f, 0.00759876f, 0.03600077f, 0.10936068f, 0.21300554f, \
                0.26601173f, 0.21300554f, 0.10936068f, 0.03600077f, 0.00759876f, 0.00102838f}

// h-pass: update 4 outputs of one row from one staged column (i = local col idx)
#define COLUP(I, AB) do {                                                     \
    if ((I) >= 1 && (I) <= 14) {                                              \
        v2f ab_ = (AB);                                                       \
        v2f sq_ = ab_ * ab_;                                                  \
        float axb_ = ab_.x * ab_.y;                                           \
        _Pragma("unroll")                                                     \
        for (int k_ = 0; k_ < 4; ++k_) {                                      \
            int j_ = (I) - 1 - k_;                                            \
            if (j_ >= 0 && j_ <= 10) {                                        \
                v2f w2_ = {g[j_], g[j_]};                                     \
                s01[k_] = __builtin_elementwise_fma(w2_, ab_, s01[k_]);       \
                s23[k_] = __builtin_elementwise_fma(w2_, sq_, s23[k_]);       \
                s4[k_]  = fmaf(g[j_], axb_, s4[k_]);                          \
            }                                                                 \
        }                                                                     \
    }                                                                         \
} while (0)

// v-pass: update 8 column-outputs from one h-row (I = row idx within window)
#define ROWUP(I, H01, H23) do {                                               \
    v2f h01_ = (H01); v2f h23_ = (H23); float e_ = q4[(I)];                   \
    _Pragma("unroll")                                                         \
    for (int k_ = 0; k_ < 8; ++k_) {                                          \
        int j_ = (I) - k_;                                                    \
        if (j_ >= 0 && j_ <= 10) {                                            \
            v2f w2_ = {g[j_], g[j_]};                                         \
            a01[k_] = __builtin_elementwise_fma(w2_, h01_, a01[k_]);          \
            a23[k_] = __builtin_elementwise_fma(w2_, h23_, a23[k_]);          \
            a4a[k_] = fmaf(g[j_], e_, a4a[k_]);                               \
        }                                                                     \
    }                                                                         \
} while (0)

__global__ __launch_bounds__(BLK, 4) void ssim_main(const float* __restrict__ img1,
                                                    const float* __restrict__ img2,
                                                    float* __restrict__ partial) {
    // interleaved input staging: lab4[r][q] = (a0,b0,a1,b1) pairs, 48 cols/row
    __shared__ v4f  lab4[IH * LAB4STR];     // 29600 B
    // h-pass outputs, column-major [col][row] for contiguous v-pass reads
    __shared__ v2f  p01[TW * PSTR];         // 19968 B : (sx, sy)
    __shared__ v2f  p23[TW * PSTR];         // 19968 B : (sxx, syy)
    __shared__ float p4[TW * P4STR];        //  9728 B : sxy
    __shared__ float wsum[8];               // total ~79.3 KB -> 2 blocks/CU

    const int tid = threadIdx.x;
    const int tx0 = blockIdx.x * TW;
    const int ty0 = blockIdx.y * TH;
    const size_t base = (size_t)blockIdx.z * (size_t)(IMG_H * IMG_W);
    const float g[WIN] = G_INIT;

    // ---- stage: 74 rows x 12 aligned float4 chunks, interleaved (a,b) ----
    const bool interior = (blockIdx.x >= 1) & (blockIdx.x <= (IMG_W / TW - 2)) &
                          (blockIdx.y >= 1) & (blockIdx.y <= (IMG_H / TH - 2));
    for (int t = tid; t < IH * 12; t += BLK) {
        int r = t / 12, k = t - r * 12;
        v4f a = (v4f){0.f, 0.f, 0.f, 0.f};
        v4f b = (v4f){0.f, 0.f, 0.f, 0.f};
        int gr = ty0 + r - PAD;
        int gc0 = tx0 - 8 + 4 * k;
        if (interior) {
            const size_t off = base + (size_t)gr * IMG_W + gc0;
            a = *(const v4f*)(img1 + off);
            b = *(const v4f*)(img2 + off);
        } else if ((unsigned)gr < (unsigned)IMG_H && gc0 >= 0 && gc0 <= IMG_W - 4) {
            // chunks are wholly in or out of bounds (512 % 4 == 0, gc0 % 4 == 0)
            const size_t off = base + (size_t)gr * IMG_W + gc0;
            a = *(const v4f*)(img1 + off);
            b = *(const v4f*)(img2 + off);
        }
        v4f* dst = &lab4[r * LAB4STR + 2 * k];
        dst[0] = (v4f){a.x, b.x, a.y, b.y};
        dst[1] = (v4f){a.z, b.z, a.w, b.w};
    }
    __syncthreads();

    // ---- horizontal 11-tap pass: 4 outputs/thread, packed (a,b) math ----
    // remap: 8 consecutive lanes -> 8 different rows, same col group
    for (int t = tid; t < 640; t += BLK) {
        int gq = (t >> 3) & 7;                     // col group: outputs 4*gq..4*gq+3
        int r  = (t & 7) | ((t >> 6) << 3);        // 0..79
        if (r < IH) {
            v2f s01[4], s23[4];
            float s4[4];
#pragma unroll
            for (int k = 0; k < 4; ++k) { s01[k] = (v2f){0.f, 0.f}; s23[k] = (v2f){0.f, 0.f}; s4[k] = 0.f; }
            // staged v2f cols 4*gq+2 .. 4*gq+17 = 8 float4 quads; local i = col-(4gq+2)
            const v4f* src = &lab4[r * LAB4STR + 2 * gq + 1];
#pragma unroll
            for (int q = 0; q < 8; ++q) {
                v4f f = src[q];
                COLUP(2 * q,     ((v2f){f.x, f.y}));
                COLUP(2 * q + 1, ((v2f){f.z, f.w}));
            }
#pragma unroll
            for (int k = 0; k < 4; ++k) {
                int oc = 4 * gq + k;
                p01[oc * PSTR + r] = s01[k];
                p23[oc * PSTR + r] = s23[k];
                p4 [oc * P4STR + r] = s4[k];
            }
        }
    }
    __syncthreads();

    // ---- vertical 11-tap pass + SSIM: 8 rows/thread, contiguous b128 reads ----
    const float C2v = 0.0009f;  // (0.03 * 1.0)^2
    float acc = 0.f;
    if (tid < 256) {
        int c  = tid & 31;
        int r0 = (tid >> 5) << 3;              // 0,8,..,56
        v2f a01[8], a23[8];
        float a4a[8];
#pragma unroll
        for (int k = 0; k < 8; ++k) { a01[k] = (v2f){0.f, 0.f}; a23[k] = (v2f){0.f, 0.f}; a4a[k] = 0.f; }
        float q4[20];
#pragma unroll
        for (int q = 0; q < 5; ++q) {
            v4f f = *(const v4f*)&p4[c * P4STR + r0 + 4 * q];
            q4[4 * q + 0] = f.x; q4[4 * q + 1] = f.y; q4[4 * q + 2] = f.z; q4[4 * q + 3] = f.w;
        }
#pragma unroll
        for (int q = 0; q < 9; ++q) {
            v4f f01 = *(const v4f*)&p01[c * PSTR + r0 + 2 * q];
            v4f f23 = *(const v4f*)&p23[c * PSTR + r0 + 2 * q];
            ROWUP(2 * q,     ((v2f){f01.x, f01.y}), ((v2f){f23.x, f23.y}));
            ROWUP(2 * q + 1, ((v2f){f01.z, f01.w}), ((v2f){f23.z, f23.w}));
        }
#pragma unroll
        for (int k = 0; k < 8; ++k) {
            float sx = a01[k].x, sy = a01[k].y;
            float sxx = a23[k].x, syy = a23[k].y;
            float s1  = fmaf(-sx, sx, sxx);
            float s2  = fmaf(-sy, sy, syy);
            float s12 = fmaf(-sx, sy, a4a[k]);
            float sig = __builtin_amdgcn_sqrtf(fabsf(s1)) * __builtin_amdgcn_sqrtf(fabsf(s2));
            acc += __fdividef(s12 + C2v, sig + C2v);
        }
    }

    // ---- block reduction -> one float partial per block ----
#pragma unroll
    for (int off = 32; off > 0; off >>= 1) acc += __shfl_down(acc, off, 64);
    int wave = tid >> 6;
    if ((tid & 63) == 0) wsum[wave] = acc;
    __syncthreads();
    if (tid == 0) {
        float b = 0.f;
#pragma unroll
        for (int w = 0; w < BLK / 64; ++w) b += wsum[w];
        int bid = (blockIdx.z * gridDim.y + blockIdx.y) * gridDim.x + blockIdx.x;
        partial[bid] = b;
    }
}

// ---------------- final reduction ----------------
__global__ __launch_bounds__(1024) void ssim_final(const float* __restrict__ partial,
                                                   int n, float* __restrict__ out,
                                                   double inv_total) {
    __shared__ double wsd[16];
    double s = 0.0;
    const v4f* p4v = (const v4f*)partial;
    for (int i = threadIdx.x; i < n / 4; i += 1024) {
        v4f v = p4v[i];
        s += (double)v.x + (double)v.y + (double)v.z + (double)v.w;
    }
#pragma unroll
    for (int off = 32; off > 0; off >>= 1) s += __shfl_down(s, off, 64);
    int wave = threadIdx.x >> 6;
    if ((threadIdx.x & 63) == 0) wsd[wave] = s;
    __syncthreads();
    if (threadIdx.x == 0) {
        double t = 0.0;
#pragma unroll
        for (int w = 0; w < 16; ++w) t += wsd[w];
        out[0] = (float)(t * inv_total);
    }
}

extern "C" void kernel_launch(void* const* d_in, const int* in_sizes, int n_in,
                              void* d_out, int out_size, void* d_ws, size_t ws_size,
                              hipStream_t stream) {
    const float* img1 = (const float*)d_in[0];
    const float* img2 = (const float*)d_in[1];
    float* out = (float*)d_out;
    float* partial = (float*)d_ws;

    const int total = in_sizes[0];                  // 32*3*512*512
    const int nc = total / (IMG_H * IMG_W);         // 96 images of 512x512

    dim3 grid(IMG_W / TW, IMG_H / TH, nc);          // 16 x 8 x 96 = 12288 blocks
    const int nblocks = grid.x * grid.y * grid.z;   // divisible by 4

    ssim_main<<<grid, BLK, 0, stream>>>(img1, img2, partial);
    ssim_final<<<1, 1024, 0, stream>>>(partial, nblocks, out, 1.0 / (double)total);
}